// Round 4
// baseline (678.177 us; speedup 1.0000x reference)
//
#include <hip/hip_runtime.h>

typedef unsigned short u16;
typedef unsigned int   u32;
typedef __bf16 bf16x8 __attribute__((ext_vector_type(8)));
typedef float  f32x4  __attribute__((ext_vector_type(4)));

// ---------- helpers ----------
__device__ __forceinline__ float bf2f(u16 v){ u32 u = ((u32)v) << 16; float f; __builtin_memcpy(&f,&u,4); return f; }
__device__ __forceinline__ u16 f2bf(float f){ u32 u; __builtin_memcpy(&u,&f,4); u32 r = (u + 0x7FFFu + ((u>>16)&1u)) >> 16; return (u16)r; }
__device__ __forceinline__ float silu(float v){ return v / (1.f + __expf(-v)); }

__device__ __forceinline__ void gload_lds16(const u16* g, u16* l){
  __builtin_amdgcn_global_load_lds((const __attribute__((address_space(1))) void*)g,
                                   (__attribute__((address_space(3))) void*)l, 16, 0, 0);
}

#define FENCE asm volatile("" ::: "memory")
#define BARRIER do{ FENCE; __builtin_amdgcn_s_barrier(); FENCE; }while(0)

// Geometry: B=16, C1=128, C2=256, H=W=128, padded spatial 130x130 (1-px zero halo)
#define HP 130
#define XPIX 128
#define YPIX 256
#define XIMG (HP*HP*XPIX)
#define YIMG (HP*HP*YPIX)

// ---------- small prep kernels ----------
__global__ void prep_coef(const float* __restrict__ gamma, const float* __restrict__ beta,
                          const float* __restrict__ mean,  const float* __restrict__ var,
                          const float* __restrict__ b1, float2* __restrict__ coefA, float2* __restrict__ coefB){
  int c = threadIdx.x;
  float s = gamma[c] * rsqrtf(var[c] + 1e-5f);
  float t = beta[c] - mean[c] * s;
  coefA[c] = make_float2(s, t);
  coefB[c] = make_float2(s, b1[c] * s + t);
}

// w3p[n][k] bf16, k = (kh*3+kw)*128 + c
__global__ void repack_w3(const float* __restrict__ w, u16* __restrict__ w3p){
  int idx = blockIdx.x*256 + threadIdx.x;
  int n = idx / 1152, k = idx % 1152;
  int tap = k >> 7, c = k & 127;
  int kh = tap / 3, kw = tap % 3;
  w3p[idx] = f2bf(w[((n*128 + c)*3 + kh)*3 + kw]);
}

__global__ void repack_w1(const float* __restrict__ w, u16* __restrict__ w1p){
  int idx = blockIdx.x*256 + threadIdx.x;
  w1p[idx] = f2bf(w[idx]);
}

__device__ __forceinline__ void halo_pix(int pi, int& hp, int& wp){
  if (pi < 130){ hp = 0; wp = pi; }
  else if (pi < 260){ hp = 129; wp = pi - 130; }
  else { int j = pi - 260; hp = 1 + (j >> 1); wp = (j & 1) ? 129 : 0; }
}
__global__ void zero_halos(u16* __restrict__ xpad, u16* __restrict__ ypad, int cimg){
  int idx = blockIdx.x*256 + threadIdx.x;
  const int NX = cimg*516*16;
  uint4 z = make_uint4(0u,0u,0u,0u);
  if (idx < NX){
    int b = idx / (516*16), rr = idx % (516*16);
    int pi = rr >> 4, cch = rr & 15, hp, wp;
    halo_pix(pi, hp, wp);
    *(uint4*)(xpad + (((size_t)b*HP + hp)*HP + wp)*XPIX + cch*8) = z;
  } else {
    idx -= NX;
    if (idx < cimg*516*32){
      int b = idx / (516*32), rr = idx % (516*32);
      int pi = rr >> 5, cch = rr & 31, hp, wp;
      halo_pix(pi, hp, wp);
      *(uint4*)(ypad + (((size_t)b*HP + hp)*HP + wp)*YPIX + cch*8) = z;
    }
  }
}

// fp32 NCHW -> padded bf16 NHWC transpose
__global__ __launch_bounds__(256) void transpose_x(const float* __restrict__ x, u16* __restrict__ xpad, int b0){
  __shared__ u16 s[64][66];
  const int tid = threadIdx.x, bid = blockIdx.x;
  const int ct = bid & 1, wt = (bid >> 1) & 1, row = bid >> 2;
  const int bl = row >> 7, h = row & 127;
  const int c0 = ct << 6, w0 = wt << 6;
  {
    const int lw = tid & 63, lc4 = tid >> 6;
    const size_t xb = ((size_t)(b0 + bl)*128)*16384 + (size_t)h*128 + w0 + lw;
    #pragma unroll
    for (int r = 0; r < 16; ++r){
      int c = r*4 + lc4;
      s[c][lw] = f2bf(x[xb + (size_t)(c0 + c)*16384]);
    }
  }
  __syncthreads();
  {
    const int lw = tid >> 5, lcp = (tid & 31) << 1;
    const size_t pb = ((size_t)bl*HP + h + 1)*HP;
    #pragma unroll
    for (int r = 0; r < 8; ++r){
      int w = r*8 + lw;
      u32 v = (u32)s[lcp][w] | ((u32)s[lcp+1][w] << 16);
      *(u32*)(xpad + (pb + (w0 + w + 1))*XPIX + c0 + lcp) = v;
    }
  }
}

// ---------- stage A: conv3x3 implicit GEMM ----------
// Tile = 128 px (one output row) x 256 ch, BK=32, 4 waves (wave = 128px x 64ch).
// 48 KiB LDS -> 2-3 independent blocks/CU; independent barriers decorrelate the
// blocks so one block's LDS-read drain overlaps the sibling's MFMA burst (m114).
// Per k-tile: 6 stage gloads (next tile) + 12 ds_read_b128 + 32 independent MFMA
// + vmcnt(0)+barrier (issue-to-wait distance = full tile -> ~free).
// LDS rows are 64 B (4 chunks of 16 B); swizzle chunk ^= (row>>1)&3 gives perfect
// 2-lane/bank reads (free) and is applied via pre-swizzled global sources.

__device__ __forceinline__ int offA_of(int kt){
  int tap = kt >> 2;
  int kh = (tap*11) >> 5;            // tap/3 for tap<=9
  int kw = tap - kh*3;
  return kh*(HP*XPIX) + kw*XPIX + ((kt & 3) << 5);
}

__global__ __launch_bounds__(256, 2) void convA(const u16* __restrict__ xpad, const u16* __restrict__ w3p,
                                                const float2* __restrict__ coefA, u16* __restrict__ ypad){
  __shared__ u16 sA[2][4096];   // [128 px][32 k]
  __shared__ u16 sB[2][8192];   // [256 n][32 k]
  const int t = threadIdx.x;
  const int nwg = gridDim.x;
  const int bidl = (blockIdx.x & 7)*(nwg >> 3) + (blockIdx.x >> 3);  // XCD swizzle, nwg%8==0
  const int bl = bidl >> 7, h = bidl & 127;
  const int lane = t & 63, wn = t >> 6;           // 4 waves = 4 channel groups of 64
  const int quad = lane >> 4, l16 = lane & 15;
  const u16* ximg = xpad + (size_t)bl * XIMG;

  // staging descriptors (pre-swizzled global, linear LDS dest)
  const u16* gA[2]; int lAo[2];
  #pragma unroll
  for (int q = 0; q < 2; ++q){
    int id = t + q*256, p = id >> 2, c = id & 3, cs = c ^ ((p >> 1) & 3);
    gA[q] = ximg + (size_t)(h*HP + p)*XPIX + cs*8;
    lAo[q] = id*8;
  }
  const u16* gB[4]; int lBo[4];
  #pragma unroll
  for (int q = 0; q < 4; ++q){
    int id = t + q*256, n = id >> 2, c = id & 3, cs = c ^ ((n >> 1) & 3);
    gB[q] = w3p + (size_t)n*1152 + cs*8;
    lBo[q] = id*8;
  }

  // fragment bases: row*32 + (quad ^ ((l16>>1)&3))*8 ; +i*512 / +j*512 immediates
  const int xq = (quad ^ ((l16 >> 1) & 3)) << 3;
  const u32 fAb = (u32)l16*32 + xq;
  const u32 fBb = (u32)(wn*64 + l16)*32 + xq;

  f32x4 acc[8][4];
  #pragma unroll
  for (int i = 0; i < 8; ++i)
    #pragma unroll
    for (int j = 0; j < 4; ++j){ f32x4 z = {0.f,0.f,0.f,0.f}; acc[i][j] = z; }

  // prologue: stage k-tile 0 into buf0
  {
    const int o = offA_of(0);
    gload_lds16(gA[0] + o, sA[0] + lAo[0]);
    gload_lds16(gA[1] + o, sA[0] + lAo[1]);
    #pragma unroll
    for (int q = 0; q < 4; ++q) gload_lds16(gB[q], sB[0] + lBo[q]);
    asm volatile("s_waitcnt vmcnt(0)" ::: "memory");
  }
  BARRIER;

  for (int kt = 0; kt < 36; ++kt){
    const int pr = kt & 1;
    const u16* A = sA[pr]; const u16* B = sB[pr];
    u16* An = sA[pr ^ 1]; u16* Bn = sB[pr ^ 1];

    // stage next tile first (flies under reads+MFMA)
    if (kt < 35){
      const int ao = offA_of(kt + 1), bo = (kt + 1) << 5;
      gload_lds16(gA[0] + ao, An + lAo[0]);
      gload_lds16(gA[1] + ao, An + lAo[1]);
      #pragma unroll
      for (int q = 0; q < 4; ++q) gload_lds16(gB[q] + bo, Bn + lBo[q]);
    }

    // fragment reads in consumption order: a0, b0-b3, a1..a7
    bf16x8 a[8], b[4];
    a[0] = *(const bf16x8*)(A + fAb);
    #pragma unroll
    for (int j = 0; j < 4; ++j) b[j] = *(const bf16x8*)(B + fBb + j*512);
    #pragma unroll
    for (int i = 1; i < 8; ++i) a[i] = *(const bf16x8*)(A + fAb + i*512);

    __builtin_amdgcn_s_setprio(1);
    #pragma unroll
    for (int i = 0; i < 8; ++i)
      #pragma unroll
      for (int j = 0; j < 4; ++j)
        acc[i][j] = __builtin_amdgcn_mfma_f32_16x16x32_bf16(a[i], b[j], acc[i][j], 0, 0, 0);
    __builtin_amdgcn_s_setprio(0);

    asm volatile("s_waitcnt vmcnt(0)" ::: "memory");
    BARRIER;
  }

  // epilogue: BN + SiLU -> ypad (NHWC bf16)
  // D[p = i*16 + quad*4 + r][ch = wn*64 + j*16 + l16]
  float2 co[4];
  #pragma unroll
  for (int j = 0; j < 4; ++j) co[j] = coefA[wn*64 + j*16 + l16];
  const size_t ybase = ((size_t)(bl*HP + h + 1))*HP*YPIX;
  #pragma unroll
  for (int i = 0; i < 8; ++i)
    #pragma unroll
    for (int r = 0; r < 4; ++r){
      const int p = i*16 + quad*4 + r;
      u16* dst = ypad + ybase + (size_t)(p + 1)*YPIX + wn*64;
      #pragma unroll
      for (int j = 0; j < 4; ++j){
        float v = acc[i][j][r]*co[j].x + co[j].y;
        dst[j*16 + l16] = f2bf(silu(v));
      }
    }
}

// ---------- stage B: shift + conv1x1 + bias + BN + residual + SiLU -> out (NCHW fp32) ----------
// [128px][64ch] LDS tiles, XOR-swizzled, 4 K-steps of 32 MFMA, double-buffered,
// 64 KiB LDS -> 2 blocks/CU.
__global__ __launch_bounds__(256, 2) void convB(const u16* __restrict__ ypad, const u16* __restrict__ w1p,
                                                const float2* __restrict__ coefB, float* __restrict__ out, int b0){
  __shared__ u16 sAct[2][8192];
  __shared__ u16 sW[2][8192];
  const int tid = threadIdx.x;
  const int nwg = gridDim.x;
  const int bidl = (blockIdx.x & 7)*(nwg >> 3) + (blockIdx.x >> 3);  // XCD swizzle
  const int nt = bidl & 1, row = bidl >> 1;
  const int bl = row >> 7, h = row & 127;
  const int n0 = nt << 7;
  const int lane = tid & 63, wave = tid >> 6;
  const int wc = wave & 1, wpx = wave >> 1;
  const int quad = lane >> 4, l16 = lane & 15;

  const size_t imgy = (size_t)bl * YIMG;

  const u16* gact[4]; const u16* gwt[4]; int ldst[4];
  #pragma unroll
  for (int l = 0; l < 4; ++l){
    int id = l*256 + tid;
    int p = id >> 3, c = id & 7;
    gact[l] = ypad + imgy + (size_t)(h*HP)*YPIX + (size_t)p*YPIX + ((c ^ (p & 7)) << 3);
    gwt[l]  = w1p + (size_t)(n0 + p)*256 + ((c ^ (p & 7)) << 3);
    ldst[l] = id*8;
  }

  u32 fW[4][2], fAc[4][2];
  #pragma unroll
  for (int i = 0; i < 4; ++i)
    #pragma unroll
    for (int k = 0; k < 2; ++k){
      int rn = wc*64 + i*16 + l16;
      fW[i][k] = rn*64 + (((k*4 + quad) ^ (rn & 7)) << 3);
      int rp = wpx*64 + i*16 + l16;
      fAc[i][k] = rp*64 + (((k*4 + quad) ^ (rp & 7)) << 3);
    }

  f32x4 acc[4][4];
  #pragma unroll
  for (int i = 0; i < 4; ++i)
    #pragma unroll
    for (int j = 0; j < 4; ++j){ f32x4 zz = {0.f,0.f,0.f,0.f}; acc[i][j] = zz; }

  // prologue: stage g=0 (shift g0: pad(h+1, w+0))
  {
    const int aoff = (1*HP + 0)*YPIX + 0;
    #pragma unroll
    for (int l = 0; l < 4; ++l){
      gload_lds16(gact[l] + aoff, sAct[0] + ldst[l]);
      gload_lds16(gwt[l],         sW[0]   + ldst[l]);
    }
    asm volatile("s_waitcnt vmcnt(0)" ::: "memory");
  }
  BARRIER;

  #pragma unroll
  for (int g = 0; g < 4; ++g){
    const int pr = g & 1;
    if (g < 3){
      const int gg = g + 1;
      const int dhp = (gg == 1) ? 2 : ((gg == 3) ? 0 : 1);
      const int dwp = (gg == 0) ? 0 : ((gg == 2) ? 2 : 1);
      const int aoff = (dhp*HP + dwp)*YPIX + gg*64;
      const int woff = gg*64;
      #pragma unroll
      for (int l = 0; l < 4; ++l){
        gload_lds16(gact[l] + aoff, sAct[pr^1] + ldst[l]);
        gload_lds16(gwt[l] + woff,  sW[pr^1]   + ldst[l]);
      }
    }
    bf16x8 wf[4][2], af[4][2];
    #pragma unroll
    for (int i = 0; i < 4; ++i){
      wf[i][0] = *(const bf16x8*)(sW[pr] + fW[i][0]);
      wf[i][1] = *(const bf16x8*)(sW[pr] + fW[i][1]);
      af[i][0] = *(const bf16x8*)(sAct[pr] + fAc[i][0]);
      af[i][1] = *(const bf16x8*)(sAct[pr] + fAc[i][1]);
    }
    __builtin_amdgcn_s_setprio(1);
    #pragma unroll
    for (int i = 0; i < 4; ++i)
      #pragma unroll
      for (int j = 0; j < 4; ++j){
        acc[i][j] = __builtin_amdgcn_mfma_f32_16x16x32_bf16(wf[i][0], af[j][0], acc[i][j], 0, 0, 0);
        acc[i][j] = __builtin_amdgcn_mfma_f32_16x16x32_bf16(wf[i][1], af[j][1], acc[i][j], 0, 0, 0);
      }
    __builtin_amdgcn_s_setprio(0);
    asm volatile("s_waitcnt vmcnt(0)" ::: "memory");
    BARRIER;
  }

  const size_t ybase = ((size_t)(bl*HP + h + 1))*HP*YPIX;
  const size_t obase = (size_t)(b0 + bl)*256*16384 + (size_t)h*128;
  #pragma unroll
  for (int i = 0; i < 4; ++i){
    const int chb = n0 + wc*64 + i*16 + quad*4;
    const float2 c0 = coefB[chb+0], c1 = coefB[chb+1], c2 = coefB[chb+2], c3 = coefB[chb+3];
    float* ob = out + obase + (size_t)chb*16384;
    #pragma unroll
    for (int j = 0; j < 4; ++j){
      const int p = wpx*64 + j*16 + l16;
      const ushort4 rv = *(const ushort4*)&ypad[ybase + (size_t)(p + 1)*YPIX + chb];
      ob[p]             = silu(acc[i][j][0]*c0.x + c0.y + bf2f(rv.x));
      ob[16384 + p]     = silu(acc[i][j][1]*c1.x + c1.y + bf2f(rv.y));
      ob[2*16384 + p]   = silu(acc[i][j][2]*c2.x + c2.y + bf2f(rv.z));
      ob[3*16384 + p]   = silu(acc[i][j][3]*c3.x + c3.y + bf2f(rv.w));
    }
  }
}

// ---------- launch ----------
extern "C" void kernel_launch(void* const* d_in, const int* in_sizes, int n_in,
                              void* d_out, int out_size, void* d_ws, size_t ws_size,
                              hipStream_t stream){
  const float* x  = (const float*)d_in[0];
  const float* w3 = (const float*)d_in[1];
  const float* w1 = (const float*)d_in[2];
  const float* b1 = (const float*)d_in[3];
  const float* gm = (const float*)d_in[4];
  const float* bt = (const float*)d_in[5];
  const float* mn = (const float*)d_in[6];
  const float* vr = (const float*)d_in[7];
  float* outp = (float*)d_out;

  char* ws = (char*)d_ws;
  float2* coefA = (float2*)ws;
  float2* coefB = coefA + 256;
  u16*    w3p   = (u16*)(ws + 4096);
  u16*    w1p   = (u16*)(ws + 4096 + 589824);
  const size_t fixed = 4096 + 589824 + 131072;
  int cimg = 16;
  while (cimg > 1 && fixed + (size_t)cimg*12979200ull > ws_size) cimg >>= 1;
  u16* xpad = (u16*)(ws + fixed);
  u16* ypad = (u16*)(ws + fixed + (size_t)cimg*4326400ull);

  prep_coef<<<1, 256, 0, stream>>>(gm, bt, mn, vr, b1, coefA, coefB);
  repack_w3<<<1152, 256, 0, stream>>>(w3, w3p);
  repack_w1<<<256, 256, 0, stream>>>(w1, w1p);
  {
    int nthr = cimg*516*48;
    zero_halos<<<(nthr + 255)/256, 256, 0, stream>>>(xpad, ypad, cimg);
  }
  for (int b0 = 0; b0 < 16; b0 += cimg){
    transpose_x<<<4*128*cimg, 256, 0, stream>>>(x, xpad, b0);
    convA<<<128*cimg, 256, 0, stream>>>(xpad, w3p, coefA, ypad);
    convB<<<2*128*cimg, 256, 0, stream>>>(ypad, w1p, coefB, outp, b0);
  }
}

// Round 5
// 651.354 us; speedup vs baseline: 1.0412x; 1.0412x over previous
//
#include <hip/hip_runtime.h>

typedef unsigned short u16;
typedef unsigned int   u32;
typedef __bf16 bf16x8 __attribute__((ext_vector_type(8)));
typedef float  f32x4  __attribute__((ext_vector_type(4)));

// ---------- helpers ----------
__device__ __forceinline__ float bf2f(u16 v){ u32 u = ((u32)v) << 16; float f; __builtin_memcpy(&f,&u,4); return f; }
__device__ __forceinline__ u16 f2bf(float f){ u32 u; __builtin_memcpy(&u,&f,4); u32 r = (u + 0x7FFFu + ((u>>16)&1u)) >> 16; return (u16)r; }
__device__ __forceinline__ float silu(float v){ return v / (1.f + __expf(-v)); }

__device__ __forceinline__ void gload_lds16(const u16* g, u16* l){
  __builtin_amdgcn_global_load_lds((const __attribute__((address_space(1))) void*)g,
                                   (__attribute__((address_space(3))) void*)l, 16, 0, 0);
}

#define FENCE asm volatile("" ::: "memory")
#define BARRIER do{ FENCE; __builtin_amdgcn_s_barrier(); FENCE; }while(0)

// Geometry: B=16, C1=128, C2=256, H=W=128, padded spatial 130x130 (1-px zero halo)
#define HP 130
#define XPIX 128
#define YPIX 256
#define XIMG (HP*HP*XPIX)
#define YIMG (HP*HP*YPIX)

// ---------- small prep kernels ----------
__global__ void prep_coef(const float* __restrict__ gamma, const float* __restrict__ beta,
                          const float* __restrict__ mean,  const float* __restrict__ var,
                          const float* __restrict__ b1, float2* __restrict__ coefA, float2* __restrict__ coefB){
  int c = threadIdx.x;
  float s = gamma[c] * rsqrtf(var[c] + 1e-5f);
  float t = beta[c] - mean[c] * s;
  coefA[c] = make_float2(s, t);
  coefB[c] = make_float2(s, b1[c] * s + t);
}

// w3p[n][k] bf16, k = (kh*3+kw)*128 + c
__global__ void repack_w3(const float* __restrict__ w, u16* __restrict__ w3p){
  int idx = blockIdx.x*256 + threadIdx.x;
  int n = idx / 1152, k = idx % 1152;
  int tap = k >> 7, c = k & 127;
  int kh = tap / 3, kw = tap % 3;
  w3p[idx] = f2bf(w[((n*128 + c)*3 + kh)*3 + kw]);
}

__global__ void repack_w1(const float* __restrict__ w, u16* __restrict__ w1p){
  int idx = blockIdx.x*256 + threadIdx.x;
  w1p[idx] = f2bf(w[idx]);
}

__device__ __forceinline__ void halo_pix(int pi, int& hp, int& wp){
  if (pi < 130){ hp = 0; wp = pi; }
  else if (pi < 260){ hp = 129; wp = pi - 130; }
  else { int j = pi - 260; hp = 1 + (j >> 1); wp = (j & 1) ? 129 : 0; }
}
__global__ void zero_halos(u16* __restrict__ xpad, u16* __restrict__ ypad, int cimg){
  int idx = blockIdx.x*256 + threadIdx.x;
  const int NX = cimg*516*16;
  uint4 z = make_uint4(0u,0u,0u,0u);
  if (idx < NX){
    int b = idx / (516*16), rr = idx % (516*16);
    int pi = rr >> 4, cch = rr & 15, hp, wp;
    halo_pix(pi, hp, wp);
    *(uint4*)(xpad + (((size_t)b*HP + hp)*HP + wp)*XPIX + cch*8) = z;
  } else {
    idx -= NX;
    if (idx < cimg*516*32){
      int b = idx / (516*32), rr = idx % (516*32);
      int pi = rr >> 5, cch = rr & 31, hp, wp;
      halo_pix(pi, hp, wp);
      *(uint4*)(ypad + (((size_t)b*HP + hp)*HP + wp)*YPIX + cch*8) = z;
    }
  }
}

// fp32 NCHW -> padded bf16 NHWC transpose.
// One block per (image,h). Phase 1: wave reads a full contiguous 128-w row per c
// (float2/lane = 512B bursts). Phase 2: writes one pixel's 128 channels as a
// contiguous 256B burst. LDS [128][130] (+2 pad -> conflict-free column reads).
__global__ __launch_bounds__(256) void transpose_x(const float* __restrict__ x, u16* __restrict__ xpad, int b0){
  __shared__ u16 s[128][130];
  const int tid = threadIdx.x;
  const int bl = blockIdx.x >> 7, h = blockIdx.x & 127;
  const int lane = tid & 63, wv = tid >> 6;
  const float2* src = (const float2*)(x + ((size_t)(b0 + bl)*128)*16384 + (size_t)h*128);
  #pragma unroll
  for (int it = 0; it < 32; ++it){
    const int c = it*4 + wv;
    float2 v = src[(size_t)c*8192 + lane];
    s[c][2*lane]   = f2bf(v.x);
    s[c][2*lane+1] = f2bf(v.y);
  }
  __syncthreads();
  u16* dst = xpad + (((size_t)bl*HP + h + 1)*HP + 1)*XPIX;   // (h+1, w=1) base
  #pragma unroll
  for (int it = 0; it < 32; ++it){
    const int w = it*4 + wv;
    u32 v = (u32)s[2*lane][w] | ((u32)s[2*lane+1][w] << 16);
    *(u32*)(dst + (size_t)w*XPIX + 2*lane) = v;
  }
}

// ---------- stage A: conv3x3 implicit GEMM, 256x256 tile, BK=64 ----------
// (R3 version verbatim — best measured: 193 us.)
// 2 phases per K-tile, 2 barriers/tile, persistent wgs (BPW bands), counted vmcnt.

__device__ __forceinline__ int offA_of(int Ts){
  int tap = Ts >> 1;
  int kh = (tap*11) >> 5;            // tap/3 for tap<=9
  int kw = tap - kh*3;
  return kh*(HP*XPIX) + kw*XPIX + ((Ts & 1) << 6);
}

__global__ __launch_bounds__(512, 2) void convA(const u16* __restrict__ xpad, const u16* __restrict__ w3p,
                                                const float2* __restrict__ coefA, u16* __restrict__ ypad,
                                                int BPW){
  __shared__ u16 sA[2][16384];
  __shared__ u16 sB[2][16384];
  const int t = threadIdx.x;
  const int nwg = gridDim.x;
  const int w = (blockIdx.x & 7)*(nwg >> 3) + (blockIdx.x >> 3);   // XCD-contiguous (nwg%8==0)
  const int band0 = w * BPW;
  const int bl = band0 >> 6;                 // BPW | 64 -> bl uniform per wg
  int h0 = (band0 & 63) << 1;
  const int lane = t & 63, wave = t >> 6;
  const int wm = wave & 1, wn = wave >> 1;   // 2(M) x 4(N) waves
  const int quad = lane >> 4, l16 = lane & 15;
  const int lc = t & 7;
  const u16* ximg = xpad + (size_t)bl * XIMG;

  // staging descriptors: [half][q] -> global base (pre-swizzled), LDS elem offset
  const u16* gA[2][2]; int lA[2][2];
  const u16* gB[2][2]; int lB[2][2];
  #pragma unroll
  for (int ho = 0; ho < 2; ++ho)
    #pragma unroll
    for (int q = 0; q < 2; ++q){
      int r = ((t >> 6) << 4) + (q << 3) + ((t >> 3) & 7);
      int p = (ho << 6) + r + (r & 64);                  // ho=0: rows{0-63,128-191}
      gA[ho][q] = ximg + (size_t)((h0 + (p >> 7))*HP + (p & 127))*XPIX + ((lc ^ (p & 7)) << 3);
      lA[ho][q] = p*64 + lc*8;
      int n = ((r >> 5) << 6) + (ho << 5) + (r & 31);    // ho=0: n%64<32
      gB[ho][q] = w3p + (size_t)n*1152 + ((lc ^ (n & 7)) << 3);
      lB[ho][q] = n*64 + lc*8;
    }

  // fragment LDS offsets (elements), swizzled
  u32 fA[2][4][2], fB[4][2];
  #pragma unroll
  for (int hf = 0; hf < 2; ++hf)
    #pragma unroll
    for (int i = 0; i < 4; ++i)
      #pragma unroll
      for (int c = 0; c < 2; ++c){
        int row = wm*128 + hf*64 + i*16 + l16;
        fA[hf][i][c] = row*64 + (((c*4 + quad) ^ (row & 7)) << 3);
      }
  #pragma unroll
  for (int j = 0; j < 4; ++j)
    #pragma unroll
    for (int c = 0; c < 2; ++c){
      int row = wn*64 + j*16 + l16;
      fB[j][c] = row*64 + (((c*4 + quad) ^ (row & 7)) << 3);
    }

  f32x4 acc[8][4];
  #pragma unroll
  for (int i = 0; i < 8; ++i)
    #pragma unroll
    for (int j = 0; j < 4; ++j){ f32x4 z = {0.f,0.f,0.f,0.f}; acc[i][j] = z; }

  // prologue: stage tile 0 fully into buf0
  {
    gload_lds16(gA[0][0], sA[0] + lA[0][0]); gload_lds16(gA[0][1], sA[0] + lA[0][1]);
    gload_lds16(gB[0][0], sB[0] + lB[0][0]); gload_lds16(gB[0][1], sB[0] + lB[0][1]);
    gload_lds16(gB[1][0], sB[0] + lB[1][0]); gload_lds16(gB[1][1], sB[0] + lB[1][1]);
    gload_lds16(gA[1][0], sA[0] + lA[1][0]); gload_lds16(gA[1][1], sA[0] + lA[1][1]);
    asm volatile("s_waitcnt vmcnt(0)" ::: "memory");
  }
  BARRIER;

  const int UTOT = 18 * BPW;
  int tn = 0;
  for (int u = 0; u < UTOT; ++u){
    const int pr = u & 1;
    const u16* A = sA[pr]; const u16* B = sB[pr];
    u16* An = sA[pr ^ 1]; u16* Bn = sB[pr ^ 1];
    const bool last = (u == UTOT - 1);
    const int ntl = (tn == 17) ? 0 : tn + 1;
    if (tn == 17 && !last){                      // advance A descriptors to next band
      #pragma unroll
      for (int ho = 0; ho < 2; ++ho)
        #pragma unroll
        for (int q = 0; q < 2; ++q) gA[ho][q] += 2*HP*XPIX;
    }
    const int aoff = offA_of(ntl), boff = ntl*64;

    bf16x8 a[4][2], b[4][2];
    // ---- P0: read a0 + all B; stage (u+1).A.h0,B.h0; MFMA i=0..3 ----
    #pragma unroll
    for (int i = 0; i < 4; ++i){
      a[i][0] = *(const bf16x8*)(A + fA[0][i][0]);
      a[i][1] = *(const bf16x8*)(A + fA[0][i][1]);
    }
    #pragma unroll
    for (int j = 0; j < 4; ++j){
      b[j][0] = *(const bf16x8*)(B + fB[j][0]);
      b[j][1] = *(const bf16x8*)(B + fB[j][1]);
    }
    if (!last){
      gload_lds16(gA[0][0] + aoff, An + lA[0][0]); gload_lds16(gA[0][1] + aoff, An + lA[0][1]);
      gload_lds16(gB[0][0] + boff, Bn + lB[0][0]); gload_lds16(gB[0][1] + boff, Bn + lB[0][1]);
    }
    __builtin_amdgcn_s_setprio(1);
    #pragma unroll
    for (int i = 0; i < 4; ++i)
      #pragma unroll
      for (int j = 0; j < 4; ++j){
        acc[i][j] = __builtin_amdgcn_mfma_f32_16x16x32_bf16(a[i][0], b[j][0], acc[i][j], 0, 0, 0);
        acc[i][j] = __builtin_amdgcn_mfma_f32_16x16x32_bf16(a[i][1], b[j][1], acc[i][j], 0, 0, 0);
      }
    __builtin_amdgcn_s_setprio(0);
    if (last) asm volatile("s_waitcnt vmcnt(0)" ::: "memory");
    else      asm volatile("s_waitcnt vmcnt(4)" ::: "memory");
    BARRIER;

    // ---- P1: read a1; stage (u+1).B.h1,A.h1; MFMA i=4..7 ----
    #pragma unroll
    for (int i = 0; i < 4; ++i){
      a[i][0] = *(const bf16x8*)(A + fA[1][i][0]);
      a[i][1] = *(const bf16x8*)(A + fA[1][i][1]);
    }
    if (!last){
      gload_lds16(gB[1][0] + boff, Bn + lB[1][0]); gload_lds16(gB[1][1] + boff, Bn + lB[1][1]);
      gload_lds16(gA[1][0] + aoff, An + lA[1][0]); gload_lds16(gA[1][1] + aoff, An + lA[1][1]);
    }
    __builtin_amdgcn_s_setprio(1);
    #pragma unroll
    for (int i = 0; i < 4; ++i)
      #pragma unroll
      for (int j = 0; j < 4; ++j){
        acc[4+i][j] = __builtin_amdgcn_mfma_f32_16x16x32_bf16(a[i][0], b[j][0], acc[4+i][j], 0, 0, 0);
        acc[4+i][j] = __builtin_amdgcn_mfma_f32_16x16x32_bf16(a[i][1], b[j][1], acc[4+i][j], 0, 0, 0);
      }
    __builtin_amdgcn_s_setprio(0);
    if (!last) asm volatile("s_waitcnt vmcnt(2)" ::: "memory");
    BARRIER;

    if (tn == 17){
      // epilogue: BN + SiLU -> ypad ; overlaps next band's staged loads in flight
      float2 co[4];
      #pragma unroll
      for (int j = 0; j < 4; ++j) co[j] = coefA[wn*64 + j*16 + l16];
      #pragma unroll
      for (int ig = 0; ig < 8; ++ig){
        const int pb = wm*128 + ig*16 + quad*4;
        #pragma unroll
        for (int r = 0; r < 4; ++r){
          const int p = pb + r;
          const int hh = h0 + (p >> 7), ww = p & 127;
          u16* dst = ypad + ((size_t)(bl*HP + hh + 1)*HP + (ww + 1))*YPIX + wn*64;
          #pragma unroll
          for (int j = 0; j < 4; ++j){
            float v = acc[ig][j][r]*co[j].x + co[j].y;
            dst[j*16 + l16] = f2bf(silu(v));
          }
        }
      }
      asm volatile("s_waitcnt vmcnt(0)" ::: "memory");   // drain stores so counted vmcnt stays valid
      h0 += 2;
      tn = 0;
      #pragma unroll
      for (int i = 0; i < 8; ++i)
        #pragma unroll
        for (int j = 0; j < 4; ++j){ f32x4 z = {0.f,0.f,0.f,0.f}; acc[i][j] = z; }
    } else ++tn;
  }
}

// ---------- stage B: shift + conv1x1 + bias + BN + residual + SiLU -> out (NCHW fp32) ----------
// [128px][64ch] LDS tiles, XOR-swizzled, 4 K-steps of 32 MFMA, double-buffered,
// 64 KiB LDS -> 2 blocks/CU.
__global__ __launch_bounds__(256, 2) void convB(const u16* __restrict__ ypad, const u16* __restrict__ w1p,
                                                const float2* __restrict__ coefB, float* __restrict__ out, int b0){
  __shared__ u16 sAct[2][8192];
  __shared__ u16 sW[2][8192];
  const int tid = threadIdx.x;
  const int nwg = gridDim.x;
  const int bidl = (blockIdx.x & 7)*(nwg >> 3) + (blockIdx.x >> 3);  // XCD swizzle
  const int nt = bidl & 1, row = bidl >> 1;
  const int bl = row >> 7, h = row & 127;
  const int n0 = nt << 7;
  const int lane = tid & 63, wave = tid >> 6;
  const int wc = wave & 1, wpx = wave >> 1;
  const int quad = lane >> 4, l16 = lane & 15;

  const size_t imgy = (size_t)bl * YIMG;

  const u16* gact[4]; const u16* gwt[4]; int ldst[4];
  #pragma unroll
  for (int l = 0; l < 4; ++l){
    int id = l*256 + tid;
    int p = id >> 3, c = id & 7;
    gact[l] = ypad + imgy + (size_t)(h*HP)*YPIX + (size_t)p*YPIX + ((c ^ (p & 7)) << 3);
    gwt[l]  = w1p + (size_t)(n0 + p)*256 + ((c ^ (p & 7)) << 3);
    ldst[l] = id*8;
  }

  u32 fW[4][2], fAc[4][2];
  #pragma unroll
  for (int i = 0; i < 4; ++i)
    #pragma unroll
    for (int k = 0; k < 2; ++k){
      int rn = wc*64 + i*16 + l16;
      fW[i][k] = rn*64 + (((k*4 + quad) ^ (rn & 7)) << 3);
      int rp = wpx*64 + i*16 + l16;
      fAc[i][k] = rp*64 + (((k*4 + quad) ^ (rp & 7)) << 3);
    }

  f32x4 acc[4][4];
  #pragma unroll
  for (int i = 0; i < 4; ++i)
    #pragma unroll
    for (int j = 0; j < 4; ++j){ f32x4 zz = {0.f,0.f,0.f,0.f}; acc[i][j] = zz; }

  // prologue: stage g=0 (shift g0: pad(h+1, w+0))
  {
    const int aoff = (1*HP + 0)*YPIX + 0;
    #pragma unroll
    for (int l = 0; l < 4; ++l){
      gload_lds16(gact[l] + aoff, sAct[0] + ldst[l]);
      gload_lds16(gwt[l],         sW[0]   + ldst[l]);
    }
    asm volatile("s_waitcnt vmcnt(0)" ::: "memory");
  }
  BARRIER;

  #pragma unroll
  for (int g = 0; g < 4; ++g){
    const int pr = g & 1;
    if (g < 3){
      const int gg = g + 1;
      const int dhp = (gg == 1) ? 2 : ((gg == 3) ? 0 : 1);
      const int dwp = (gg == 0) ? 0 : ((gg == 2) ? 2 : 1);
      const int aoff = (dhp*HP + dwp)*YPIX + gg*64;
      const int woff = gg*64;
      #pragma unroll
      for (int l = 0; l < 4; ++l){
        gload_lds16(gact[l] + aoff, sAct[pr^1] + ldst[l]);
        gload_lds16(gwt[l] + woff,  sW[pr^1]   + ldst[l]);
      }
    }
    bf16x8 wf[4][2], af[4][2];
    #pragma unroll
    for (int i = 0; i < 4; ++i){
      wf[i][0] = *(const bf16x8*)(sW[pr] + fW[i][0]);
      wf[i][1] = *(const bf16x8*)(sW[pr] + fW[i][1]);
      af[i][0] = *(const bf16x8*)(sAct[pr] + fAc[i][0]);
      af[i][1] = *(const bf16x8*)(sAct[pr] + fAc[i][1]);
    }
    __builtin_amdgcn_s_setprio(1);
    #pragma unroll
    for (int i = 0; i < 4; ++i)
      #pragma unroll
      for (int j = 0; j < 4; ++j){
        acc[i][j] = __builtin_amdgcn_mfma_f32_16x16x32_bf16(wf[i][0], af[j][0], acc[i][j], 0, 0, 0);
        acc[i][j] = __builtin_amdgcn_mfma_f32_16x16x32_bf16(wf[i][1], af[j][1], acc[i][j], 0, 0, 0);
      }
    __builtin_amdgcn_s_setprio(0);
    asm volatile("s_waitcnt vmcnt(0)" ::: "memory");
    BARRIER;
  }

  const size_t ybase = ((size_t)(bl*HP + h + 1))*HP*YPIX;
  const size_t obase = (size_t)(b0 + bl)*256*16384 + (size_t)h*128;
  #pragma unroll
  for (int i = 0; i < 4; ++i){
    const int chb = n0 + wc*64 + i*16 + quad*4;
    const float2 c0 = coefB[chb+0], c1 = coefB[chb+1], c2 = coefB[chb+2], c3 = coefB[chb+3];
    float* ob = out + obase + (size_t)chb*16384;
    #pragma unroll
    for (int j = 0; j < 4; ++j){
      const int p = wpx*64 + j*16 + l16;
      const ushort4 rv = *(const ushort4*)&ypad[ybase + (size_t)(p + 1)*YPIX + chb];
      ob[p]             = silu(acc[i][j][0]*c0.x + c0.y + bf2f(rv.x));
      ob[16384 + p]     = silu(acc[i][j][1]*c1.x + c1.y + bf2f(rv.y));
      ob[2*16384 + p]   = silu(acc[i][j][2]*c2.x + c2.y + bf2f(rv.z));
      ob[3*16384 + p]   = silu(acc[i][j][3]*c3.x + c3.y + bf2f(rv.w));
    }
  }
}

// ---------- launch ----------
extern "C" void kernel_launch(void* const* d_in, const int* in_sizes, int n_in,
                              void* d_out, int out_size, void* d_ws, size_t ws_size,
                              hipStream_t stream){
  const float* x  = (const float*)d_in[0];
  const float* w3 = (const float*)d_in[1];
  const float* w1 = (const float*)d_in[2];
  const float* b1 = (const float*)d_in[3];
  const float* gm = (const float*)d_in[4];
  const float* bt = (const float*)d_in[5];
  const float* mn = (const float*)d_in[6];
  const float* vr = (const float*)d_in[7];
  float* outp = (float*)d_out;

  char* ws = (char*)d_ws;
  float2* coefA = (float2*)ws;
  float2* coefB = coefA + 256;
  u16*    w3p   = (u16*)(ws + 4096);
  u16*    w1p   = (u16*)(ws + 4096 + 589824);
  const size_t fixed = 4096 + 589824 + 131072;
  int cimg = 16;
  while (cimg > 1 && fixed + (size_t)cimg*12979200ull > ws_size) cimg >>= 1;
  u16* xpad = (u16*)(ws + fixed);
  u16* ypad = (u16*)(ws + fixed + (size_t)cimg*4326400ull);

  prep_coef<<<1, 256, 0, stream>>>(gm, bt, mn, vr, b1, coefA, coefB);
  repack_w3<<<1152, 256, 0, stream>>>(w3, w3p);
  repack_w1<<<256, 256, 0, stream>>>(w1, w1p);
  {
    int nthr = cimg*516*48;
    zero_halos<<<(nthr + 255)/256, 256, 0, stream>>>(xpad, ypad, cimg);
  }
  const int bands = 64*cimg;
  const int BPW = (bands >= 1024) ? 4 : (bands >= 512 ? 2 : 1);   // BPW | 64
  const int nwgA = bands / BPW;                                    // %8 == 0
  for (int b0 = 0; b0 < 16; b0 += cimg){
    transpose_x<<<128*cimg, 256, 0, stream>>>(x, xpad, b0);
    convA<<<nwgA, 512, 0, stream>>>(xpad, w3p, coefA, ypad, BPW);
    convB<<<2*128*cimg, 256, 0, stream>>>(ypad, w1p, coefB, outp, b0);
  }
}